// Round 6
// baseline (1928.646 us; speedup 1.0000x reference)
//
#include <hip/hip_runtime.h>
#include <hip/hip_cooperative_groups.h>
#include <math.h>

namespace cg = cooperative_groups;

#define B 64
#define N 1024
#define D 256
#define H 256
#define G3 768            // 3*H
#define NUM_BAGS (B*N)
#define OUTW (D+H)
#define NBLK 256          // persistent blocks, one per CU (cooperative)
#define GM 16             // nodes per group (MFMA M)

typedef _Float16 h2_t __attribute__((ext_vector_type(2)));
typedef _Float16 f16x8 __attribute__((ext_vector_type(8)));
typedef float f32x4 __attribute__((ext_vector_type(4)));
typedef unsigned int uint32;

__device__ __forceinline__ float sigmoidf_(float x) { return 1.0f / (1.0f + expf(-x)); }

__device__ __forceinline__ void ld8(const float* __restrict__ p, float* d) {
    float4 a = *(const float4*)p, b = *(const float4*)(p + 4);
    d[0]=a.x; d[1]=a.y; d[2]=a.z; d[3]=a.w; d[4]=b.x; d[5]=b.y; d[6]=b.z; d[7]=b.w;
}

// ---------------------------------------------------------------------------
// Kernel 1: w_ihT transpose, whh16 row-major f16 pack, zero hist/nlv
// whh16[n*128 + m] = pack_f16(w_hh[n][2m], w_hh[n][2m+1])  (row-major in k)
// ---------------------------------------------------------------------------
__global__ void k_prep(const float* __restrict__ w_ih, const float* __restrict__ w_hh,
                       float* __restrict__ w_ihT, uint32* __restrict__ whh16,
                       int* __restrict__ hist, int* __restrict__ nlv) {
    int idx = blockIdx.x * blockDim.x + threadIdx.x;
    if (idx < G3 * D) {
        int j = idx / D;
        int d = idx % D;
        w_ihT[d * G3 + j] = w_ih[idx];
    }
    if (idx < G3 * 128) {
        float w0 = w_hh[2 * idx];
        float w1 = w_hh[2 * idx + 1];
        h2_t v = { (_Float16)w0, (_Float16)w1 };
        whh16[idx] = __builtin_bit_cast(uint32, v);
    }
    if (idx < 1024) hist[idx] = 0;
    if (idx == 0) *nlv = 0;
}

// ---------------------------------------------------------------------------
// Kernel 1b: depth[b][i] = depth[parent]+1 + LDS histogram (spread RMWs)
// ---------------------------------------------------------------------------
__global__ void k_depth(const int* __restrict__ lp_all, int* __restrict__ depth,
                        int* __restrict__ hist) {
    __shared__ int slp[N];
    __shared__ int sd[N];
    __shared__ int lh[1024];
    int b = blockIdx.x;
    for (int t = threadIdx.x; t < N; t += 256) {
        slp[t] = lp_all[(size_t)b * N + t];
        lh[t] = 0;
    }
    __syncthreads();
    if (threadIdx.x == 0) {
        sd[0] = 0;
        for (int i = 1; i < N; ++i) {
            int p = slp[i];
            sd[i] = ((unsigned)p < (unsigned)i) ? sd[p] + 1 : 0;
        }
    }
    __syncthreads();
    for (int t = threadIdx.x; t < N; t += 256) {
        depth[(size_t)b * N + t] = sd[t];
        atomicAdd(&lh[sd[t]], 1);
    }
    __syncthreads();
    for (int t = threadIdx.x; t < 1024; t += 256)
        if (lh[t] > 0) atomicAdd(&hist[t], lh[t]);
}

// 1 block x 1024: inclusive Hillis-Steele -> exclusive base, cursor copy, nlv
__global__ void k_scan(const int* __restrict__ hist, int* __restrict__ base,
                       int* __restrict__ cursor, int* __restrict__ nlv) {
    __shared__ int tmp[1024];
    int t = threadIdx.x;
    int v = hist[t];
    tmp[t] = v;
    __syncthreads();
    for (int off = 1; off < 1024; off <<= 1) {
        int y = (t >= off) ? tmp[t - off] : 0;
        __syncthreads();
        tmp[t] += y;
        __syncthreads();
    }
    int inc = tmp[t];
    base[t] = inc - v;
    cursor[t] = inc - v;
    if (t == 1023) base[1024] = inc;
    if (v > 0) atomicMax(nlv, t + 1);
}

// ---------------------------------------------------------------------------
// Kernel 1c: LDS-staged scatter — one ranged global RMW per (block, bin)
// ---------------------------------------------------------------------------
__global__ void k_scatter(const int* __restrict__ depth, int* __restrict__ cursor,
                          int* __restrict__ order) {
    __shared__ int lh[1024];
    __shared__ int lbase[1024];
    int tid = threadIdx.x;
    int g = blockIdx.x * 256 + tid;
    int d = depth[g];
    for (int t = tid; t < 1024; t += 256) lh[t] = 0;
    __syncthreads();
    int lrank = atomicAdd(&lh[d], 1);
    __syncthreads();
    for (int t = tid; t < 1024; t += 256)
        if (lh[t] > 0) lbase[t] = atomicAdd(&cursor[t], lh[t]);
    __syncthreads();
    order[lbase[d] + lrank] = g;
}

// ---------------------------------------------------------------------------
// Kernel 2: TE2/PE2 with scale+bias FOLDED:
//  type rows:  TE2[t][k] = 4*(type_emb@w_ihT) + bi[k] + bh[k]   (k < 512)
//              TE2[t][k] = 4*(...) + bi[k]                      (k >= 512)
//  pos rows:   PE2[c][k] = 0.25*(pos@w_ihT)
// ---------------------------------------------------------------------------
__global__ void k_table_gemm(const float* __restrict__ type_emb, const float* __restrict__ pos_table,
                             const float* __restrict__ w_ihT,
                             const float* __restrict__ b_ih, const float* __restrict__ b_hh,
                             float* __restrict__ TE2, float* __restrict__ PE2) {
    __shared__ float row[D];
    int r = blockIdx.x;
    const float* src;
    float* dst;
    bool isType = (r < 300);
    if (isType) { src = type_emb + (size_t)r * D;          dst = TE2 + (size_t)r * G3; }
    else        { src = pos_table + (size_t)(r - 300) * D; dst = PE2 + (size_t)(r - 300) * G3; }
    int k = threadIdx.x;
    row[k] = src[k];
    __syncthreads();
    float a0 = 0.f, a1 = 0.f, a2 = 0.f;
#pragma unroll 8
    for (int d = 0; d < D; ++d) {
        float p = row[d];
        const float* w = w_ihT + d * G3;
        a0 += p * w[k];
        a1 += p * w[k + 256];
        a2 += p * w[k + 512];
    }
    if (isType) {
        dst[k]       = 4.f * a0 + b_ih[k]       + b_hh[k];
        dst[k + 256] = 4.f * a1 + b_ih[k + 256] + b_hh[k + 256];
        dst[k + 512] = 4.f * a2 + b_ih[k + 512];
    } else {
        dst[k] = 0.25f * a0; dst[k + 256] = 0.25f * a1; dst[k + 512] = 0.25f * a2;
    }
}

// ---------------------------------------------------------------------------
// Kernel 3: output columns [0, D)
// ---------------------------------------------------------------------------
__global__ void k_embed_out(const int* __restrict__ node_types, const int* __restrict__ child_pos,
                            const int* __restrict__ node_vals, const int* __restrict__ offsets,
                            const float* __restrict__ type_emb, const float* __restrict__ pos_table,
                            const float* __restrict__ token_emb, float* __restrict__ out, int Ltot) {
    int tid = threadIdx.x;
    int bag = blockIdx.x * 4 + (tid >> 6);
    int q   = (tid & 63) * 4;
    int b = bag >> 10;
    int i = bag & 1023;
    int t = node_types[bag];
    int c = child_pos[bag];
    int start = offsets[bag];
    int end   = (bag + 1 < NUM_BAGS) ? offsets[bag + 1] : Ltot;

    float4 s = make_float4(0.f, 0.f, 0.f, 0.f);
    for (int l = start; l < end; ++l) {
        float4 v = *(const float4*)(token_emb + (size_t)node_vals[l] * D + q);
        s.x += v.x; s.y += v.y; s.z += v.z; s.w += v.w;
    }
    int cnt = end - start; if (cnt < 1) cnt = 1;
    float inv = 4.0f / (float)cnt;
    float4 a = *(const float4*)(type_emb + (size_t)t * D + q);
    float4 p = *(const float4*)(pos_table + (size_t)c * D + q);
    float4 r;
    r.x = 4.f * a.x + 0.25f * p.x + inv * s.x;
    r.y = 4.f * a.y + 0.25f * p.y + inv * s.y;
    r.z = 4.f * a.z + 0.25f * p.z + inv * s.z;
    r.w = 4.f * a.w + 0.25f * p.w + inv * s.w;
    *(float4*)(out + ((size_t)i * B + b) * OUTW + q) = r;
}

// ---------------------------------------------------------------------------
// Kernel 4: level-scheduled GRU on MFMA, STREAMED weights.
// R5 post-mortem: a 192-VGPR weight array spills (compiler caps at 128) and
// the scratch re-load was the bottleneck (FETCH 333 MB, 52 us/group). Here
// B-fragments stream from whh16 (global) inside the K-loop: fully coalesced
// (lanes (lu,lr) cover whole 64B lines), L2-resident (393 KB/XCD), amortized
// over GM=16 nodes. Live VGPRs ~85 -> no spill. Parent f32 values are kept
// in registers from phase 2 to phase 4 (same thread mapping), halving the
// `out` parent reads.
// ---------------------------------------------------------------------------
__global__ void __launch_bounds__(512, 4) k_gru_lvl(
        const int* __restrict__ node_types, const int* __restrict__ child_pos,
        const int* __restrict__ last_parent,
        const float* __restrict__ TE2, const float* __restrict__ PE2,
        const uint32* __restrict__ whh16,
        const float* __restrict__ b_hh,
        float* __restrict__ out,
        const int* __restrict__ order, const int* __restrict__ lvlbase,
        const int* __restrict__ nlvp) {
    __shared__ __align__(16) _Float16 spA[GM * 264];   // h parents f16, row stride 264
    __shared__ float gbuf[GM * 772];                   // gates f32, row stride 772
    __shared__ int   meta[GM][4];                      // g, parent(-1 invalid), type, cpos

    cg::grid_group grid = cg::this_grid();

    const int j = threadIdx.x;
    const int lane = j & 63;
    const int w = j >> 6;                 // wave 0..7, owns cols [w*96, w*96+96)
    const int lr = lane & 15;             // fragment row/col index
    const int lu = lane >> 4;             // fragment k-group
    const int nlv = *nlvp;

    // per-wave weight base: row (w*96 + lr), k-offset lu*4 dwords
    const uint32* wbase = whh16 + (size_t)(w * 96 + lr) * 128 + lu * 4;

    for (int L = 0; L < nlv; ++L) {
        const int s0 = lvlbase[L], e = lvlbase[L + 1];
        const int nG = (e - s0 + GM - 1) / GM;
        for (int q = blockIdx.x; q < nG; q += NBLK) {
            const int k0 = s0 + q * GM;
            const int cn = min(GM, e - k0);

            // ---- phase 1: meta ----
            if (j < GM) {
                int g = (j < cn) ? order[k0 + j] : -1;
                int pp = -1, ty = 0, cpos = 0;
                if (g >= 0) {
                    const int i = g & (N - 1);
                    const int p = last_parent[g];
                    if (i > 0 && (unsigned)p < (unsigned)i) pp = p;
                    ty = node_types[g]; cpos = child_pos[g];
                }
                meta[j][0] = g; meta[j][1] = pp; meta[j][2] = ty; meta[j][3] = cpos;
            }
            __syncthreads();

            // ---- phase 2: gather parent h -> f16 LDS tile, keep f32 in regs ----
            float pv[8];
            {
                const int n = j >> 5, c0 = (j & 31) * 8;
                const int g = meta[n][0], p = meta[n][1];
#pragma unroll
                for (int u = 0; u < 8; ++u) pv[u] = 0.f;
                if (p >= 0) {
                    const int b = g >> 10;
                    ld8(out + ((size_t)p * B + b) * OUTW + D + c0, pv);
                }
                h2_t v0 = {(_Float16)pv[0], (_Float16)pv[1]};
                h2_t v1 = {(_Float16)pv[2], (_Float16)pv[3]};
                h2_t v2 = {(_Float16)pv[4], (_Float16)pv[5]};
                h2_t v3 = {(_Float16)pv[6], (_Float16)pv[7]};
                uint4 pk = { __builtin_bit_cast(uint32, v0), __builtin_bit_cast(uint32, v1),
                             __builtin_bit_cast(uint32, v2), __builtin_bit_cast(uint32, v3) };
                *(uint4*)(&spA[n * 264 + c0]) = pk;
            }
            __syncthreads();

            // ---- phase 3: MFMA K-loop, B-fragments streamed from L2 ----
            {
                f32x4 acc[6];
#pragma unroll
                for (int t = 0; t < 6; ++t) acc[t] = (f32x4){0.f, 0.f, 0.f, 0.f};
#pragma unroll
                for (int s = 0; s < 8; ++s) {
                    const uint4 a4 = *(const uint4*)(&spA[lr * 264 + s * 32 + lu * 8]);
                    const f16x8 af = __builtin_bit_cast(f16x8, a4);
#pragma unroll
                    for (int t = 0; t < 6; ++t) {
                        const uint4 bwf = *(const uint4*)(wbase + (size_t)(t * 16) * 128 + s * 16);
                        acc[t] = __builtin_amdgcn_mfma_f32_16x16x32_f16(
                            af, __builtin_bit_cast(f16x8, bwf), acc[t], 0, 0, 0);
                    }
                }
#pragma unroll
                for (int t = 0; t < 6; ++t) {
#pragma unroll
                    for (int qd = 0; qd < 4; ++qd) {
                        const int row = lu * 4 + qd;
                        const int col = w * 96 + t * 16 + lr;
                        gbuf[row * 772 + col] = acc[t][qd];
                    }
                }
            }
            __syncthreads();

            // ---- phase 4: activation + h store (pv from regs) ----
            {
                const int n = j >> 5, c0 = (j & 31) * 8;
                const int g = meta[n][0];
                if (g >= 0) {
                    const int b = g >> 10, i = g & (N - 1);
                    const int ty = meta[n][2], cp_ = meta[n][3];
                    const float* gb = gbuf + n * 772;
                    const float* te = TE2 + (size_t)ty * G3;
                    const float* pe = PE2 + (size_t)cp_ * G3;
                    float ga[8], ta[8], pa[8], rr[8], zz[8], hr[8];
                    ld8(gb + c0, ga); ld8(te + c0, ta); ld8(pe + c0, pa);
#pragma unroll
                    for (int u = 0; u < 8; ++u) rr[u] = sigmoidf_(ga[u] + ta[u] + pa[u]);
                    ld8(gb + 256 + c0, ga); ld8(te + 256 + c0, ta); ld8(pe + 256 + c0, pa);
#pragma unroll
                    for (int u = 0; u < 8; ++u) zz[u] = sigmoidf_(ga[u] + ta[u] + pa[u]);
                    ld8(gb + 512 + c0, ga); ld8(te + 512 + c0, ta); ld8(pe + 512 + c0, pa);
                    float bn[8];
                    ld8(b_hh + 512 + c0, bn);
#pragma unroll
                    for (int u = 0; u < 8; ++u) {
                        const float nn = tanhf(ta[u] + pa[u] + rr[u] * (ga[u] + bn[u]));
                        hr[u] = (1.f - zz[u]) * nn + zz[u] * pv[u];
                    }
                    float* orow = out + ((size_t)i * B + b) * OUTW + D + c0;
                    *(float4*)orow       = make_float4(hr[0], hr[1], hr[2], hr[3]);
                    *(float4*)(orow + 4) = make_float4(hr[4], hr[5], hr[6], hr[7]);
                }
            }
            __syncthreads();
        }
        // ---- level barrier ----
        if (L + 1 < nlv) grid.sync();
    }
}

// ---------------------------------------------------------------------------
extern "C" void kernel_launch(void* const* d_in, const int* in_sizes, int n_in,
                              void* d_out, int out_size, void* d_ws, size_t ws_size,
                              hipStream_t stream) {
    const int*   node_types  = (const int*)d_in[0];
    const int*   node_vals   = (const int*)d_in[1];
    const int*   offsets     = (const int*)d_in[2];
    const int*   last_parent = (const int*)d_in[3];
    const int*   child_pos   = (const int*)d_in[4];
    const float* type_emb    = (const float*)d_in[5];
    const float* pos_table   = (const float*)d_in[6];
    const float* token_emb   = (const float*)d_in[7];
    const float* w_ih        = (const float*)d_in[8];
    const float* w_hh        = (const float*)d_in[9];
    const float* b_ih        = (const float*)d_in[10];
    const float* b_hh        = (const float*)d_in[11];
    float* out = (float*)d_out;

    // Workspace: w_ihT | TE2 | PE2 | whh16 | depth | order | hist | lvlbase |
    //            cursor | nlv   (~5.7 MB)
    float*  ws      = (float*)d_ws;
    float*  w_ihT   = ws;
    float*  TE2     = w_ihT + (size_t)G3 * D;
    float*  PE2     = TE2 + (size_t)300 * G3;
    uint32* whh16   = (uint32*)(PE2 + (size_t)1000 * G3);
    int*    depth   = (int*)(whh16 + (size_t)G3 * 128);
    int*    order   = depth + NUM_BAGS;
    int*    hist    = order + NUM_BAGS;
    int*    lvlbase = hist + 1024;          // 1025 ints
    int*    cursor  = lvlbase + 1025;
    int*    nlv     = cursor + 1024;
    int Ltot = in_sizes[1];

    hipLaunchKernelGGL(k_prep, dim3((G3 * D + 255) / 256), dim3(256), 0, stream,
                       w_ih, w_hh, w_ihT, whh16, hist, nlv);
    hipLaunchKernelGGL(k_depth, dim3(B), dim3(256), 0, stream, last_parent, depth, hist);
    hipLaunchKernelGGL(k_scan, dim3(1), dim3(1024), 0, stream, hist, lvlbase, cursor, nlv);
    hipLaunchKernelGGL(k_scatter, dim3(NUM_BAGS / 256), dim3(256), 0, stream, depth, cursor, order);
    hipLaunchKernelGGL(k_table_gemm, dim3(1300), dim3(256), 0, stream,
                       type_emb, pos_table, w_ihT, b_ih, b_hh, TE2, PE2);
    hipLaunchKernelGGL(k_embed_out, dim3(NUM_BAGS / 4), dim3(256), 0, stream,
                       node_types, child_pos, node_vals, offsets,
                       type_emb, pos_table, token_emb, out, Ltot);

    void* args[] = {
        (void*)&node_types, (void*)&child_pos, (void*)&last_parent,
        (void*)&TE2, (void*)&PE2, (void*)&whh16,
        (void*)&b_hh, (void*)&out,
        (void*)&order, (void*)&lvlbase, (void*)&nlv
    };
    hipLaunchCooperativeKernel((const void*)k_gru_lvl, dim3(NBLK), dim3(512),
                               args, 0, stream);
}

// Round 7
// 1414.464 us; speedup vs baseline: 1.3635x; 1.3635x over previous
//
#include <hip/hip_runtime.h>
#include <hip/hip_cooperative_groups.h>
#include <math.h>

namespace cg = cooperative_groups;

#define B 64
#define N 1024
#define D 256
#define H 256
#define G3 768            // 3*H
#define NUM_BAGS (B*N)
#define OUTW (D+H)
#define NBLK 256          // persistent blocks, one per CU (cooperative)
#define GM 16             // nodes per group (MFMA M)

typedef _Float16 h2_t __attribute__((ext_vector_type(2)));
typedef _Float16 f16x8 __attribute__((ext_vector_type(8)));
typedef float f32x4 __attribute__((ext_vector_type(4)));
typedef unsigned int uint32;

__device__ __forceinline__ float sigmoidf_(float x) { return 1.0f / (1.0f + expf(-x)); }

__device__ __forceinline__ void ld8(const float* __restrict__ p, float* d) {
    float4 a = *(const float4*)p, b = *(const float4*)(p + 4);
    d[0]=a.x; d[1]=a.y; d[2]=a.z; d[3]=a.w; d[4]=b.x; d[5]=b.y; d[6]=b.z; d[7]=b.w;
}

// ---------------------------------------------------------------------------
// Kernel 1: w_ihT transpose; wpk = per-(wave,gate) contiguous f16 weight pack:
//   global row n = g*256 + w*32 + r  (g=gate, w=wave, r=row-in-slice)
//   wpk[(((w*3+g)*32 + r)<<7) + m] = pack_f16(w_hh[n][2m], w_hh[n][2m+1])
// Each wave's per-group stream is its own contiguous 48 KB slice.
// ---------------------------------------------------------------------------
__global__ void k_prep(const float* __restrict__ w_ih, const float* __restrict__ w_hh,
                       float* __restrict__ w_ihT, uint32* __restrict__ wpk,
                       int* __restrict__ hist, int* __restrict__ nlv) {
    int idx = blockIdx.x * blockDim.x + threadIdx.x;
    if (idx < G3 * D) {
        int j = idx / D;
        int d = idx % D;
        w_ihT[d * G3 + j] = w_ih[idx];
    }
    if (idx < G3 * 128) {
        int n = idx >> 7, m = idx & 127;
        float w0 = w_hh[n * D + 2 * m];
        float w1 = w_hh[n * D + 2 * m + 1];
        h2_t v = { (_Float16)w0, (_Float16)w1 };
        int g = n >> 8, rem = n & 255, ww = rem >> 5, r = rem & 31;
        wpk[(((ww * 3 + g) * 32 + r) << 7) + m] = __builtin_bit_cast(uint32, v);
    }
    if (idx < 1024) hist[idx] = 0;
    if (idx == 0) *nlv = 0;
}

// ---------------------------------------------------------------------------
// Kernel 1b: depth[b][i] = depth[parent]+1 + LDS histogram (spread RMWs)
// ---------------------------------------------------------------------------
__global__ void k_depth(const int* __restrict__ lp_all, int* __restrict__ depth,
                        int* __restrict__ hist) {
    __shared__ int slp[N];
    __shared__ int sd[N];
    __shared__ int lh[1024];
    int b = blockIdx.x;
    for (int t = threadIdx.x; t < N; t += 256) {
        slp[t] = lp_all[(size_t)b * N + t];
        lh[t] = 0;
    }
    __syncthreads();
    if (threadIdx.x == 0) {
        sd[0] = 0;
        for (int i = 1; i < N; ++i) {
            int p = slp[i];
            sd[i] = ((unsigned)p < (unsigned)i) ? sd[p] + 1 : 0;
        }
    }
    __syncthreads();
    for (int t = threadIdx.x; t < N; t += 256) {
        depth[(size_t)b * N + t] = sd[t];
        atomicAdd(&lh[sd[t]], 1);
    }
    __syncthreads();
    for (int t = threadIdx.x; t < 1024; t += 256)
        if (lh[t] > 0) atomicAdd(&hist[t], lh[t]);
}

// 1 block x 1024: inclusive Hillis-Steele -> exclusive base, cursor copy, nlv
__global__ void k_scan(const int* __restrict__ hist, int* __restrict__ base,
                       int* __restrict__ cursor, int* __restrict__ nlv) {
    __shared__ int tmp[1024];
    int t = threadIdx.x;
    int v = hist[t];
    tmp[t] = v;
    __syncthreads();
    for (int off = 1; off < 1024; off <<= 1) {
        int y = (t >= off) ? tmp[t - off] : 0;
        __syncthreads();
        tmp[t] += y;
        __syncthreads();
    }
    int inc = tmp[t];
    base[t] = inc - v;
    cursor[t] = inc - v;
    if (t == 1023) base[1024] = inc;
    if (v > 0) atomicMax(nlv, t + 1);
}

// ---------------------------------------------------------------------------
// Kernel 1c: LDS-staged scatter — one ranged global RMW per (block, bin)
// ---------------------------------------------------------------------------
__global__ void k_scatter(const int* __restrict__ depth, int* __restrict__ cursor,
                          int* __restrict__ order) {
    __shared__ int lh[1024];
    __shared__ int lbase[1024];
    int tid = threadIdx.x;
    int g = blockIdx.x * 256 + tid;
    int d = depth[g];
    for (int t = tid; t < 1024; t += 256) lh[t] = 0;
    __syncthreads();
    int lrank = atomicAdd(&lh[d], 1);
    __syncthreads();
    for (int t = tid; t < 1024; t += 256)
        if (lh[t] > 0) lbase[t] = atomicAdd(&cursor[t], lh[t]);
    __syncthreads();
    order[lbase[d] + lrank] = g;
}

// ---------------------------------------------------------------------------
// Kernel 2: TE2 (f32, biases folded) and PE2h (f16; values O(0.12), rounding
// ~1e-4 — shrinks PE2 3.0->1.5 MB so TE2+PE2h+wpk = 2.8 MB fits per-XCD L2):
//  type rows:  TE2[t][k] = 4*(type_emb@w_ihT) + bi[k] + bh[k]   (k < 512)
//              TE2[t][k] = 4*(...) + bi[k]                      (k >= 512)
//  pos rows:   PE2h[c][k] = (f16) 0.25*(pos@w_ihT)
// ---------------------------------------------------------------------------
__global__ void k_table_gemm(const float* __restrict__ type_emb, const float* __restrict__ pos_table,
                             const float* __restrict__ w_ihT,
                             const float* __restrict__ b_ih, const float* __restrict__ b_hh,
                             float* __restrict__ TE2, _Float16* __restrict__ PE2h) {
    __shared__ float row[D];
    int r = blockIdx.x;
    const float* src;
    bool isType = (r < 300);
    src = isType ? (type_emb + (size_t)r * D) : (pos_table + (size_t)(r - 300) * D);
    int k = threadIdx.x;
    row[k] = src[k];
    __syncthreads();
    float a0 = 0.f, a1 = 0.f, a2 = 0.f;
#pragma unroll 8
    for (int d = 0; d < D; ++d) {
        float p = row[d];
        const float* w = w_ihT + d * G3;
        a0 += p * w[k];
        a1 += p * w[k + 256];
        a2 += p * w[k + 512];
    }
    if (isType) {
        float* dst = TE2 + (size_t)r * G3;
        dst[k]       = 4.f * a0 + b_ih[k]       + b_hh[k];
        dst[k + 256] = 4.f * a1 + b_ih[k + 256] + b_hh[k + 256];
        dst[k + 512] = 4.f * a2 + b_ih[k + 512];
    } else {
        _Float16* dst = PE2h + (size_t)(r - 300) * G3;
        dst[k]       = (_Float16)(0.25f * a0);
        dst[k + 256] = (_Float16)(0.25f * a1);
        dst[k + 512] = (_Float16)(0.25f * a2);
    }
}

// ---------------------------------------------------------------------------
// Kernel 3: output columns [0, D)
// ---------------------------------------------------------------------------
__global__ void k_embed_out(const int* __restrict__ node_types, const int* __restrict__ child_pos,
                            const int* __restrict__ node_vals, const int* __restrict__ offsets,
                            const float* __restrict__ type_emb, const float* __restrict__ pos_table,
                            const float* __restrict__ token_emb, float* __restrict__ out, int Ltot) {
    int tid = threadIdx.x;
    int bag = blockIdx.x * 4 + (tid >> 6);
    int q   = (tid & 63) * 4;
    int b = bag >> 10;
    int i = bag & 1023;
    int t = node_types[bag];
    int c = child_pos[bag];
    int start = offsets[bag];
    int end   = (bag + 1 < NUM_BAGS) ? offsets[bag + 1] : Ltot;

    float4 s = make_float4(0.f, 0.f, 0.f, 0.f);
    for (int l = start; l < end; ++l) {
        float4 v = *(const float4*)(token_emb + (size_t)node_vals[l] * D + q);
        s.x += v.x; s.y += v.y; s.z += v.z; s.w += v.w;
    }
    int cnt = end - start; if (cnt < 1) cnt = 1;
    float inv = 4.0f / (float)cnt;
    float4 a = *(const float4*)(type_emb + (size_t)t * D + q);
    float4 p = *(const float4*)(pos_table + (size_t)c * D + q);
    float4 r;
    r.x = 4.f * a.x + 0.25f * p.x + inv * s.x;
    r.y = 4.f * a.y + 0.25f * p.y + inv * s.y;
    r.z = 4.f * a.z + 0.25f * p.z + inv * s.z;
    r.w = 4.f * a.w + 0.25f * p.w + inv * s.w;
    *(float4*)(out + ((size_t)i * B + b) * OUTW + q) = r;
}

// ---------------------------------------------------------------------------
// Kernel 4: level-scheduled MFMA GRU, wave-owns-column-slice layout.
// Wave w computes cols [w*32, w*32+32) for ALL 3 gates (6 16x16 tiles) ->
// after MFMA each lane holds r,z,n in registers for its (node,col) pairs:
// no gbuf LDS (58->8.7 KB), no gate-exchange sync. B-fragments stream from
// the per-wave contiguous wpk slice (48 KB, L2-resident; re-read each group).
// MFMA operand mapping identical to the R5 hardware-verified one.
// __launch_bounds__(512,2): the proven no-spill point (R6's (512,4) forced
// 64 VGPRs and a catastrophic scratch spill — never cap below need).
// ---------------------------------------------------------------------------
__global__ void __launch_bounds__(512, 2) k_gru_lvl(
        const int* __restrict__ node_types, const int* __restrict__ child_pos,
        const int* __restrict__ last_parent,
        const float* __restrict__ TE2, const _Float16* __restrict__ PE2h,
        const uint32* __restrict__ wpk,
        const float* __restrict__ b_hh,
        float* __restrict__ out,
        const int* __restrict__ order, const int* __restrict__ lvlbase,
        const int* __restrict__ nlvp) {
    __shared__ __align__(16) _Float16 spA[GM * 264];   // h parents f16, row stride 264
    __shared__ int meta[GM][4];                        // g, parent(-1), type, cpos

    cg::grid_group grid = cg::this_grid();

    const int j = threadIdx.x;
    const int lane = j & 63;
    const int w = j >> 6;                 // wave 0..7, owns cols [w*32, w*32+32)
    const int lr = lane & 15;
    const int lu = lane >> 4;
    const int nlv = *nlvp;

    // wave's contiguous weight slice: 3 gates x 32 rows x 128 dwords
    const uint32* wb = wpk + ((size_t)(w * 3 * 32) << 7);

    for (int L = 0; L < nlv; ++L) {
        const int s0 = lvlbase[L], e = lvlbase[L + 1];
        const int nG = (e - s0 + GM - 1) / GM;
        for (int q = blockIdx.x; q < nG; q += NBLK) {
            const int k0 = s0 + q * GM;
            const int cn = min(GM, e - k0);

            // ---- phase 1: meta ----
            if (j < GM) {
                int g = (j < cn) ? order[k0 + j] : -1;
                int pp = -1, ty = 0, cpos = 0;
                if (g >= 0) {
                    const int i = g & (N - 1);
                    const int p = last_parent[g];
                    if (i > 0 && (unsigned)p < (unsigned)i) pp = p;
                    ty = node_types[g]; cpos = child_pos[g];
                }
                meta[j][0] = g; meta[j][1] = pp; meta[j][2] = ty; meta[j][3] = cpos;
            }
            __syncthreads();

            // ---- phase 2: gather parent h -> f16 LDS tile ----
            {
                const int n = j >> 5, c0 = (j & 31) * 8;
                const int g = meta[n][0], p = meta[n][1];
                float hv[8] = {0.f,0.f,0.f,0.f,0.f,0.f,0.f,0.f};
                if (p >= 0) {
                    const int b = g >> 10;
                    ld8(out + ((size_t)p * B + b) * OUTW + D + c0, hv);
                }
                h2_t v0 = {(_Float16)hv[0], (_Float16)hv[1]};
                h2_t v1 = {(_Float16)hv[2], (_Float16)hv[3]};
                h2_t v2 = {(_Float16)hv[4], (_Float16)hv[5]};
                h2_t v3 = {(_Float16)hv[6], (_Float16)hv[7]};
                uint4 pk = { __builtin_bit_cast(uint32, v0), __builtin_bit_cast(uint32, v1),
                             __builtin_bit_cast(uint32, v2), __builtin_bit_cast(uint32, v3) };
                *(uint4*)(&spA[n * 264 + c0]) = pk;
            }
            __syncthreads();

            // ---- phase 3: MFMA K-loop (t: gate g=t>>1, half hh=t&1) ----
            f32x4 acc[6];
#pragma unroll
            for (int t = 0; t < 6; ++t) acc[t] = (f32x4){0.f, 0.f, 0.f, 0.f};
#pragma unroll
            for (int s = 0; s < 8; ++s) {
                const uint4 a4 = *(const uint4*)(&spA[lr * 264 + s * 32 + lu * 8]);
                const f16x8 af = __builtin_bit_cast(f16x8, a4);
#pragma unroll
                for (int t = 0; t < 6; ++t) {
                    const int g = t >> 1, hh = t & 1;
                    const uint4 bwf = *(const uint4*)(wb + (((g * 32 + hh * 16 + lr) << 7)
                                                           + s * 16 + lu * 4));
                    acc[t] = __builtin_amdgcn_mfma_f32_16x16x32_f16(
                        af, __builtin_bit_cast(f16x8, bwf), acc[t], 0, 0, 0);
                }
            }

            // ---- phase 4: in-register activation + h store ----
#pragma unroll
            for (int qd = 0; qd < 4; ++qd) {
                const int row = lu * 4 + qd;
                const int g = meta[row][0];
                if (g >= 0) {
                    const int b = g >> 10, i = g & (N - 1);
                    const int p = meta[row][1], ty = meta[row][2], cp_ = meta[row][3];
                    const float* te = TE2 + (size_t)ty * G3;
                    const _Float16* pe = PE2h + (size_t)cp_ * G3;
                    const float* po = (p >= 0) ? (out + ((size_t)p * B + b) * OUTW + D) : nullptr;
                    float* orow = out + ((size_t)i * B + b) * OUTW + D;
#pragma unroll
                    for (int hh = 0; hh < 2; ++hh) {
                        const int col = w * 32 + hh * 16 + lr;
                        const float rr = sigmoidf_(acc[hh][qd]     + te[col]       + (float)pe[col]);
                        const float zz = sigmoidf_(acc[2 + hh][qd] + te[256 + col] + (float)pe[256 + col]);
                        const float nn = tanhf(te[512 + col] + (float)pe[512 + col]
                                               + rr * (acc[4 + hh][qd] + b_hh[512 + col]));
                        const float pv = po ? po[col] : 0.f;
                        orow[col] = (1.f - zz) * nn + zz * pv;
                    }
                }
            }
            __syncthreads();   // protect spA/meta reuse
        }
        // ---- level barrier ----
        if (L + 1 < nlv) grid.sync();
    }
}

// ---------------------------------------------------------------------------
extern "C" void kernel_launch(void* const* d_in, const int* in_sizes, int n_in,
                              void* d_out, int out_size, void* d_ws, size_t ws_size,
                              hipStream_t stream) {
    const int*   node_types  = (const int*)d_in[0];
    const int*   node_vals   = (const int*)d_in[1];
    const int*   offsets     = (const int*)d_in[2];
    const int*   last_parent = (const int*)d_in[3];
    const int*   child_pos   = (const int*)d_in[4];
    const float* type_emb    = (const float*)d_in[5];
    const float* pos_table   = (const float*)d_in[6];
    const float* token_emb   = (const float*)d_in[7];
    const float* w_ih        = (const float*)d_in[8];
    const float* w_hh        = (const float*)d_in[9];
    const float* b_ih        = (const float*)d_in[10];
    const float* b_hh        = (const float*)d_in[11];
    float* out = (float*)d_out;

    // Workspace: w_ihT | TE2 | PE2h(f16) | wpk | depth | order | hist |
    //            lvlbase | cursor | nlv   (~4.5 MB)
    float*     ws      = (float*)d_ws;
    float*     w_ihT   = ws;
    float*     TE2     = w_ihT + (size_t)G3 * D;
    _Float16*  PE2h    = (_Float16*)(TE2 + (size_t)300 * G3);
    uint32*    wpk     = (uint32*)(PE2h + (size_t)1000 * G3);
    int*       depth   = (int*)(wpk + (size_t)G3 * 128);
    int*       order   = depth + NUM_BAGS;
    int*       hist    = order + NUM_BAGS;
    int*       lvlbase = hist + 1024;          // 1025 ints
    int*       cursor  = lvlbase + 1025;
    int*       nlv     = cursor + 1024;
    int Ltot = in_sizes[1];

    hipLaunchKernelGGL(k_prep, dim3((G3 * D + 255) / 256), dim3(256), 0, stream,
                       w_ih, w_hh, w_ihT, wpk, hist, nlv);
    hipLaunchKernelGGL(k_depth, dim3(B), dim3(256), 0, stream, last_parent, depth, hist);
    hipLaunchKernelGGL(k_scan, dim3(1), dim3(1024), 0, stream, hist, lvlbase, cursor, nlv);
    hipLaunchKernelGGL(k_scatter, dim3(NUM_BAGS / 256), dim3(256), 0, stream, depth, cursor, order);
    hipLaunchKernelGGL(k_table_gemm, dim3(1300), dim3(256), 0, stream,
                       type_emb, pos_table, w_ihT, b_ih, b_hh, TE2, PE2h);
    hipLaunchKernelGGL(k_embed_out, dim3(NUM_BAGS / 4), dim3(256), 0, stream,
                       node_types, child_pos, node_vals, offsets,
                       type_emb, pos_table, token_emb, out, Ltot);

    void* args[] = {
        (void*)&node_types, (void*)&child_pos, (void*)&last_parent,
        (void*)&TE2, (void*)&PE2h, (void*)&wpk,
        (void*)&b_hh, (void*)&out,
        (void*)&order, (void*)&lvlbase, (void*)&nlv
    };
    hipLaunchCooperativeKernel((const void*)k_gru_lvl, dim3(NBLK), dim3(512),
                               args, 0, stream);
}

// Round 8
// 922.935 us; speedup vs baseline: 2.0897x; 1.5326x over previous
//
#include <hip/hip_runtime.h>
#include <hip/hip_cooperative_groups.h>
#include <math.h>

namespace cg = cooperative_groups;

#define B 64
#define N 1024
#define D 256
#define H 256
#define G3 768            // 3*H
#define NUM_BAGS (B*N)
#define OUTW (D+H)
#define GM 16             // nodes per group (MFMA M)
#define LVL_BLOCKS 512    // per-level kernel grid (2 blocks/CU, plain launch)
#define TAIL_START 40     // levels >= this handled by cooperative tail kernel

typedef _Float16 h2_t __attribute__((ext_vector_type(2)));
typedef _Float16 f16x8 __attribute__((ext_vector_type(8)));
typedef float f32x4 __attribute__((ext_vector_type(4)));
typedef unsigned int uint32;

__device__ __forceinline__ float sigmoidf_(float x) { return 1.0f / (1.0f + expf(-x)); }

__device__ __forceinline__ void ld8(const float* __restrict__ p, float* d) {
    float4 a = *(const float4*)p, b = *(const float4*)(p + 4);
    d[0]=a.x; d[1]=a.y; d[2]=a.z; d[3]=a.w; d[4]=b.x; d[5]=b.y; d[6]=b.z; d[7]=b.w;
}

// ---------------------------------------------------------------------------
// Kernel 1: w_ihT transpose; wpk = per-(wave,gate) contiguous f16 weight pack
// ---------------------------------------------------------------------------
__global__ void k_prep(const float* __restrict__ w_ih, const float* __restrict__ w_hh,
                       float* __restrict__ w_ihT, uint32* __restrict__ wpk,
                       int* __restrict__ hist, int* __restrict__ nlv) {
    int idx = blockIdx.x * blockDim.x + threadIdx.x;
    if (idx < G3 * D) {
        int j = idx / D;
        int d = idx % D;
        w_ihT[d * G3 + j] = w_ih[idx];
    }
    if (idx < G3 * 128) {
        int n = idx >> 7, m = idx & 127;
        float w0 = w_hh[n * D + 2 * m];
        float w1 = w_hh[n * D + 2 * m + 1];
        h2_t v = { (_Float16)w0, (_Float16)w1 };
        int g = n >> 8, rem = n & 255, ww = rem >> 5, r = rem & 31;
        wpk[(((ww * 3 + g) * 32 + r) << 7) + m] = __builtin_bit_cast(uint32, v);
    }
    if (idx < 1024) hist[idx] = 0;
    if (idx == 0) *nlv = 0;
}

// ---------------------------------------------------------------------------
// Kernel 1b: depth + LDS histogram (spread RMWs)
// ---------------------------------------------------------------------------
__global__ void k_depth(const int* __restrict__ lp_all, int* __restrict__ depth,
                        int* __restrict__ hist) {
    __shared__ int slp[N];
    __shared__ int sd[N];
    __shared__ int lh[1024];
    int b = blockIdx.x;
    for (int t = threadIdx.x; t < N; t += 256) {
        slp[t] = lp_all[(size_t)b * N + t];
        lh[t] = 0;
    }
    __syncthreads();
    if (threadIdx.x == 0) {
        sd[0] = 0;
        for (int i = 1; i < N; ++i) {
            int p = slp[i];
            sd[i] = ((unsigned)p < (unsigned)i) ? sd[p] + 1 : 0;
        }
    }
    __syncthreads();
    for (int t = threadIdx.x; t < N; t += 256) {
        depth[(size_t)b * N + t] = sd[t];
        atomicAdd(&lh[sd[t]], 1);
    }
    __syncthreads();
    for (int t = threadIdx.x; t < 1024; t += 256)
        if (lh[t] > 0) atomicAdd(&hist[t], lh[t]);
}

// 1 block x 1024: scan -> lvlbase/cursor/nlv
__global__ void k_scan(const int* __restrict__ hist, int* __restrict__ base,
                       int* __restrict__ cursor, int* __restrict__ nlv) {
    __shared__ int tmp[1024];
    int t = threadIdx.x;
    int v = hist[t];
    tmp[t] = v;
    __syncthreads();
    for (int off = 1; off < 1024; off <<= 1) {
        int y = (t >= off) ? tmp[t - off] : 0;
        __syncthreads();
        tmp[t] += y;
        __syncthreads();
    }
    int inc = tmp[t];
    base[t] = inc - v;
    cursor[t] = inc - v;
    if (t == 1023) base[1024] = inc;
    if (v > 0) atomicMax(nlv, t + 1);
}

// ---------------------------------------------------------------------------
// Kernel 1c: LDS-staged scatter
// ---------------------------------------------------------------------------
__global__ void k_scatter(const int* __restrict__ depth, int* __restrict__ cursor,
                          int* __restrict__ order) {
    __shared__ int lh[1024];
    __shared__ int lbase[1024];
    int tid = threadIdx.x;
    int g = blockIdx.x * 256 + tid;
    int d = depth[g];
    for (int t = tid; t < 1024; t += 256) lh[t] = 0;
    __syncthreads();
    int lrank = atomicAdd(&lh[d], 1);
    __syncthreads();
    for (int t = tid; t < 1024; t += 256)
        if (lh[t] > 0) lbase[t] = atomicAdd(&cursor[t], lh[t]);
    __syncthreads();
    order[lbase[d] + lrank] = g;
}

// ---------------------------------------------------------------------------
// Kernel 2: TE2 (f32, biases folded) and PE2h (f16)
// ---------------------------------------------------------------------------
__global__ void k_table_gemm(const float* __restrict__ type_emb, const float* __restrict__ pos_table,
                             const float* __restrict__ w_ihT,
                             const float* __restrict__ b_ih, const float* __restrict__ b_hh,
                             float* __restrict__ TE2, _Float16* __restrict__ PE2h) {
    __shared__ float row[D];
    int r = blockIdx.x;
    const float* src;
    bool isType = (r < 300);
    src = isType ? (type_emb + (size_t)r * D) : (pos_table + (size_t)(r - 300) * D);
    int k = threadIdx.x;
    row[k] = src[k];
    __syncthreads();
    float a0 = 0.f, a1 = 0.f, a2 = 0.f;
#pragma unroll 8
    for (int d = 0; d < D; ++d) {
        float p = row[d];
        const float* w = w_ihT + d * G3;
        a0 += p * w[k];
        a1 += p * w[k + 256];
        a2 += p * w[k + 512];
    }
    if (isType) {
        float* dst = TE2 + (size_t)r * G3;
        dst[k]       = 4.f * a0 + b_ih[k]       + b_hh[k];
        dst[k + 256] = 4.f * a1 + b_ih[k + 256] + b_hh[k + 256];
        dst[k + 512] = 4.f * a2 + b_ih[k + 512];
    } else {
        _Float16* dst = PE2h + (size_t)(r - 300) * G3;
        dst[k]       = (_Float16)(0.25f * a0);
        dst[k + 256] = (_Float16)(0.25f * a1);
        dst[k + 512] = (_Float16)(0.25f * a2);
    }
}

// ---------------------------------------------------------------------------
// Kernel 3: output columns [0, D)
// ---------------------------------------------------------------------------
__global__ void k_embed_out(const int* __restrict__ node_types, const int* __restrict__ child_pos,
                            const int* __restrict__ node_vals, const int* __restrict__ offsets,
                            const float* __restrict__ type_emb, const float* __restrict__ pos_table,
                            const float* __restrict__ token_emb, float* __restrict__ out, int Ltot) {
    int tid = threadIdx.x;
    int bag = blockIdx.x * 4 + (tid >> 6);
    int q   = (tid & 63) * 4;
    int b = bag >> 10;
    int i = bag & 1023;
    int t = node_types[bag];
    int c = child_pos[bag];
    int start = offsets[bag];
    int end   = (bag + 1 < NUM_BAGS) ? offsets[bag + 1] : Ltot;

    float4 s = make_float4(0.f, 0.f, 0.f, 0.f);
    for (int l = start; l < end; ++l) {
        float4 v = *(const float4*)(token_emb + (size_t)node_vals[l] * D + q);
        s.x += v.x; s.y += v.y; s.z += v.z; s.w += v.w;
    }
    int cnt = end - start; if (cnt < 1) cnt = 1;
    float inv = 4.0f / (float)cnt;
    float4 a = *(const float4*)(type_emb + (size_t)t * D + q);
    float4 p = *(const float4*)(pos_table + (size_t)c * D + q);
    float4 r;
    r.x = 4.f * a.x + 0.25f * p.x + inv * s.x;
    r.y = 4.f * a.y + 0.25f * p.y + inv * s.y;
    r.z = 4.f * a.z + 0.25f * p.z + inv * s.z;
    r.w = 4.f * a.w + 0.25f * p.w + inv * s.w;
    *(float4*)(out + ((size_t)i * B + b) * OUTW + q) = r;
}

// ---------------------------------------------------------------------------
// GRU level body (R7-verified MFMA core, unchanged arithmetic).
// ---------------------------------------------------------------------------
__device__ __forceinline__ void gru_level_body(
        int L, int nblk,
        const int* __restrict__ node_types, const int* __restrict__ child_pos,
        const int* __restrict__ last_parent,
        const float* __restrict__ TE2, const _Float16* __restrict__ PE2h,
        const uint32* __restrict__ wpk, const float* __restrict__ b_hh,
        float* __restrict__ out,
        const int* __restrict__ order, const int* __restrict__ lvlbase,
        _Float16* spA /*GM*264*/, int (*meta)[4]) {
    const int j = threadIdx.x;
    const int lane = j & 63;
    const int w = j >> 6;
    const int lr = lane & 15;
    const int lu = lane >> 4;
    const uint32* wb = wpk + ((size_t)(w * 3 * 32) << 7);

    const int s0 = lvlbase[L], e = lvlbase[L + 1];
    const int nG = (e - s0 + GM - 1) / GM;

    for (int q = blockIdx.x; q < nG; q += nblk) {
        const int k0 = s0 + q * GM;
        const int cn = min(GM, e - k0);

        // ---- phase 1: meta ----
        if (j < GM) {
            int g = (j < cn) ? order[k0 + j] : -1;
            int pp = -1, ty = 0, cpos = 0;
            if (g >= 0) {
                const int i = g & (N - 1);
                const int p = last_parent[g];
                if (i > 0 && (unsigned)p < (unsigned)i) pp = p;
                ty = node_types[g]; cpos = child_pos[g];
            }
            meta[j][0] = g; meta[j][1] = pp; meta[j][2] = ty; meta[j][3] = cpos;
        }
        __syncthreads();

        // ---- phase 2: gather parent h -> f16 LDS tile ----
        {
            const int n = j >> 5, c0 = (j & 31) * 8;
            const int g = meta[n][0], p = meta[n][1];
            float hv[8] = {0.f,0.f,0.f,0.f,0.f,0.f,0.f,0.f};
            if (p >= 0) {
                const int b = g >> 10;
                ld8(out + ((size_t)p * B + b) * OUTW + D + c0, hv);
            }
            h2_t v0 = {(_Float16)hv[0], (_Float16)hv[1]};
            h2_t v1 = {(_Float16)hv[2], (_Float16)hv[3]};
            h2_t v2 = {(_Float16)hv[4], (_Float16)hv[5]};
            h2_t v3 = {(_Float16)hv[6], (_Float16)hv[7]};
            uint4 pk = { __builtin_bit_cast(uint32, v0), __builtin_bit_cast(uint32, v1),
                         __builtin_bit_cast(uint32, v2), __builtin_bit_cast(uint32, v3) };
            *(uint4*)(&spA[n * 264 + c0]) = pk;
        }
        __syncthreads();

        // ---- phase 3: MFMA K-loop ----
        f32x4 acc[6];
#pragma unroll
        for (int t = 0; t < 6; ++t) acc[t] = (f32x4){0.f, 0.f, 0.f, 0.f};
#pragma unroll
        for (int s = 0; s < 8; ++s) {
            const uint4 a4 = *(const uint4*)(&spA[lr * 264 + s * 32 + lu * 8]);
            const f16x8 af = __builtin_bit_cast(f16x8, a4);
#pragma unroll
            for (int t = 0; t < 6; ++t) {
                const int g = t >> 1, hh = t & 1;
                const uint4 bwf = *(const uint4*)(wb + (((g * 32 + hh * 16 + lr) << 7)
                                                       + s * 16 + lu * 4));
                acc[t] = __builtin_amdgcn_mfma_f32_16x16x32_f16(
                    af, __builtin_bit_cast(f16x8, bwf), acc[t], 0, 0, 0);
            }
        }

        // ---- phase 4: in-register activation + h store ----
#pragma unroll
        for (int qd = 0; qd < 4; ++qd) {
            const int row = lu * 4 + qd;
            const int g = meta[row][0];
            if (g >= 0) {
                const int b = g >> 10, i = g & (N - 1);
                const int p = meta[row][1], ty = meta[row][2], cp_ = meta[row][3];
                const float* te = TE2 + (size_t)ty * G3;
                const _Float16* pe = PE2h + (size_t)cp_ * G3;
                const float* po = (p >= 0) ? (out + ((size_t)p * B + b) * OUTW + D) : nullptr;
                float* orow = out + ((size_t)i * B + b) * OUTW + D;
#pragma unroll
                for (int hh = 0; hh < 2; ++hh) {
                    const int col = w * 32 + hh * 16 + lr;
                    const float rr = sigmoidf_(acc[hh][qd]     + te[col]       + (float)pe[col]);
                    const float zz = sigmoidf_(acc[2 + hh][qd] + te[256 + col] + (float)pe[256 + col]);
                    const float nn = tanhf(te[512 + col] + (float)pe[512 + col]
                                           + rr * (acc[4 + hh][qd] + b_hh[512 + col]));
                    const float pv = po ? po[col] : 0.f;
                    orow[col] = (1.f - zz) * nn + zz * pv;
                }
            }
        }
        __syncthreads();   // protect spA/meta reuse
    }
}

// ---------------------------------------------------------------------------
// Kernel 4a: one level per launch (plain launch, 2 blocks/CU, no grid sync —
// stream ordering between launches provides cross-XCD coherence).
// Empty levels (lvlbase[L+1]==lvlbase[L], i.e. L >= nlv) exit immediately.
// ---------------------------------------------------------------------------
__global__ void __launch_bounds__(512, 2) k_gru_level(
        const int* __restrict__ node_types, const int* __restrict__ child_pos,
        const int* __restrict__ last_parent,
        const float* __restrict__ TE2, const _Float16* __restrict__ PE2h,
        const uint32* __restrict__ wpk, const float* __restrict__ b_hh,
        float* __restrict__ out,
        const int* __restrict__ order, const int* __restrict__ lvlbase, int L) {
    __shared__ __align__(16) _Float16 spA[GM * 264];
    __shared__ int meta[GM][4];
    gru_level_body(L, LVL_BLOCKS, node_types, child_pos, last_parent,
                   TE2, PE2h, wpk, b_hh, out, order, lvlbase, spA, meta);
}

// ---------------------------------------------------------------------------
// Kernel 4b: cooperative tail for pathological depth (levels >= TAIL_START).
// Exits immediately when nlv <= TAIL_START (the common case).
// ---------------------------------------------------------------------------
__global__ void __launch_bounds__(512, 2) k_gru_tail(
        const int* __restrict__ node_types, const int* __restrict__ child_pos,
        const int* __restrict__ last_parent,
        const float* __restrict__ TE2, const _Float16* __restrict__ PE2h,
        const uint32* __restrict__ wpk, const float* __restrict__ b_hh,
        float* __restrict__ out,
        const int* __restrict__ order, const int* __restrict__ lvlbase,
        const int* __restrict__ nlvp) {
    __shared__ __align__(16) _Float16 spA[GM * 264];
    __shared__ int meta[GM][4];
    const int nlv = *nlvp;
    if (nlv <= TAIL_START) return;
    cg::grid_group grid = cg::this_grid();
    for (int L = TAIL_START; L < nlv; ++L) {
        gru_level_body(L, 256, node_types, child_pos, last_parent,
                       TE2, PE2h, wpk, b_hh, out, order, lvlbase, spA, meta);
        if (L + 1 < nlv) grid.sync();
    }
}

// ---------------------------------------------------------------------------
extern "C" void kernel_launch(void* const* d_in, const int* in_sizes, int n_in,
                              void* d_out, int out_size, void* d_ws, size_t ws_size,
                              hipStream_t stream) {
    const int*   node_types  = (const int*)d_in[0];
    const int*   node_vals   = (const int*)d_in[1];
    const int*   offsets     = (const int*)d_in[2];
    const int*   last_parent = (const int*)d_in[3];
    const int*   child_pos   = (const int*)d_in[4];
    const float* type_emb    = (const float*)d_in[5];
    const float* pos_table   = (const float*)d_in[6];
    const float* token_emb   = (const float*)d_in[7];
    const float* w_ih        = (const float*)d_in[8];
    const float* w_hh        = (const float*)d_in[9];
    const float* b_ih        = (const float*)d_in[10];
    const float* b_hh        = (const float*)d_in[11];
    float* out = (float*)d_out;

    float*     ws      = (float*)d_ws;
    float*     w_ihT   = ws;
    float*     TE2     = w_ihT + (size_t)G3 * D;
    _Float16*  PE2h    = (_Float16*)(TE2 + (size_t)300 * G3);
    uint32*    wpk     = (uint32*)(PE2h + (size_t)1000 * G3);
    int*       depth   = (int*)(wpk + (size_t)G3 * 128);
    int*       order   = depth + NUM_BAGS;
    int*       hist    = order + NUM_BAGS;
    int*       lvlbase = hist + 1024;          // 1025 ints
    int*       cursor  = lvlbase + 1025;
    int*       nlv     = cursor + 1024;
    int Ltot = in_sizes[1];

    hipLaunchKernelGGL(k_prep, dim3((G3 * D + 255) / 256), dim3(256), 0, stream,
                       w_ih, w_hh, w_ihT, wpk, hist, nlv);
    hipLaunchKernelGGL(k_depth, dim3(B), dim3(256), 0, stream, last_parent, depth, hist);
    hipLaunchKernelGGL(k_scan, dim3(1), dim3(1024), 0, stream, hist, lvlbase, cursor, nlv);
    hipLaunchKernelGGL(k_scatter, dim3(NUM_BAGS / 256), dim3(256), 0, stream, depth, cursor, order);
    hipLaunchKernelGGL(k_table_gemm, dim3(1300), dim3(256), 0, stream,
                       type_emb, pos_table, w_ihT, b_ih, b_hh, TE2, PE2h);
    hipLaunchKernelGGL(k_embed_out, dim3(NUM_BAGS / 4), dim3(256), 0, stream,
                       node_types, child_pos, node_vals, offsets,
                       type_emb, pos_table, token_emb, out, Ltot);

    // One launch per level; empty levels exit in ~2 us. Stream ordering
    // provides the inter-level dependency + cross-XCD coherence.
    for (int L = 0; L < TAIL_START; ++L) {
        hipLaunchKernelGGL(k_gru_level, dim3(LVL_BLOCKS), dim3(512), 0, stream,
                           node_types, child_pos, last_parent, TE2, PE2h, wpk, b_hh,
                           out, order, lvlbase, L);
    }
    // Cooperative tail for trees deeper than TAIL_START (normally a no-op).
    void* args[] = {
        (void*)&node_types, (void*)&child_pos, (void*)&last_parent,
        (void*)&TE2, (void*)&PE2h, (void*)&wpk,
        (void*)&b_hh, (void*)&out,
        (void*)&order, (void*)&lvlbase, (void*)&nlv
    };
    hipLaunchCooperativeKernel((const void*)k_gru_tail, dim3(256), dim3(512),
                               args, 0, stream);
}